// Round 1
// baseline (272.870 us; speedup 1.0000x reference)
//
#include <hip/hip_runtime.h>
#include <math.h>

#define N_TOK 8192
#define DIM   4096
#define NE    16
#define TOKS  (2*N_TOK)        // 16384
#define NCHUNK (TOKS/64)       // 256
#define GATE_BLOCKS 512
#define GATE_WAVES  (GATE_BLOCKS*4)  // 2048

// d_out layout (all float32):
// [0]                      l_aux
// [1 .. 16384]             token_pos_after
// [16385 .. 32768]         token_pos_before
// [32769 .. 32784]         expert_token_count
// [32785 .. 49168]         weight
#define OUT_LAUX 0
#define OUT_TPA  1
#define OUT_TPB  (1+TOKS)
#define OUT_CNT  (1+2*TOKS)
#define OUT_W    (1+2*TOKS+NE)

// K1: logits (x @ Wg^T), softmax, top-2, idx, weight, me partial sums.
// Grid: 512 blocks x 256 threads. Each wave handles 4 rows over full D.
// x read once (128 MB HBM). Wg re-read per 4-row group from L2 (512 MB L2 traffic).
__global__ __launch_bounds__(256) void k_gates(
    const float4* __restrict__ x4, const float4* __restrict__ wg4,
    int* __restrict__ idx, float* __restrict__ me_partial,
    float* __restrict__ out)
{
    const int lane  = threadIdx.x & 63;
    const int wave  = threadIdx.x >> 6;
    const int gwave = blockIdx.x * 4 + wave;
    const int row0  = gwave * 4;
    const int D4    = DIM / 4;   // 1024 float4 per row

    float acc[4][NE];
    #pragma unroll
    for (int r = 0; r < 4; ++r)
        #pragma unroll
        for (int e = 0; e < NE; ++e) acc[r][e] = 0.f;

    #pragma unroll 2
    for (int j = 0; j < 16; ++j) {
        const int col = j * 64 + lane;
        float4 xv0 = x4[(size_t)(row0 + 0) * D4 + col];
        float4 xv1 = x4[(size_t)(row0 + 1) * D4 + col];
        float4 xv2 = x4[(size_t)(row0 + 2) * D4 + col];
        float4 xv3 = x4[(size_t)(row0 + 3) * D4 + col];
        #pragma unroll
        for (int e = 0; e < NE; ++e) {
            float4 wv = wg4[e * D4 + col];
            acc[0][e] = fmaf(xv0.x, wv.x, acc[0][e]);
            acc[0][e] = fmaf(xv0.y, wv.y, acc[0][e]);
            acc[0][e] = fmaf(xv0.z, wv.z, acc[0][e]);
            acc[0][e] = fmaf(xv0.w, wv.w, acc[0][e]);
            acc[1][e] = fmaf(xv1.x, wv.x, acc[1][e]);
            acc[1][e] = fmaf(xv1.y, wv.y, acc[1][e]);
            acc[1][e] = fmaf(xv1.z, wv.z, acc[1][e]);
            acc[1][e] = fmaf(xv1.w, wv.w, acc[1][e]);
            acc[2][e] = fmaf(xv2.x, wv.x, acc[2][e]);
            acc[2][e] = fmaf(xv2.y, wv.y, acc[2][e]);
            acc[2][e] = fmaf(xv2.z, wv.z, acc[2][e]);
            acc[2][e] = fmaf(xv2.w, wv.w, acc[2][e]);
            acc[3][e] = fmaf(xv3.x, wv.x, acc[3][e]);
            acc[3][e] = fmaf(xv3.y, wv.y, acc[3][e]);
            acc[3][e] = fmaf(xv3.z, wv.z, acc[3][e]);
            acc[3][e] = fmaf(xv3.w, wv.w, acc[3][e]);
        }
    }

    // Butterfly-reduce each (row,expert) across the 64 lanes; every lane ends
    // with all 64 totals (static register indexing throughout).
    #pragma unroll
    for (int r = 0; r < 4; ++r)
        #pragma unroll
        for (int e = 0; e < NE; ++e) {
            float v = acc[r][e];
            v += __shfl_xor(v, 32); v += __shfl_xor(v, 16);
            v += __shfl_xor(v, 8);  v += __shfl_xor(v, 4);
            v += __shfl_xor(v, 2);  v += __shfl_xor(v, 1);
            acc[r][e] = v;
        }

    float meacc[NE];
    #pragma unroll
    for (int e = 0; e < NE; ++e) meacc[e] = 0.f;

    #pragma unroll
    for (int r = 0; r < 4; ++r) {
        // top-1 (strict > keeps lowest index on ties, matching lax.top_k)
        float m1 = -INFINITY; int i1 = 0;
        #pragma unroll
        for (int e = 0; e < NE; ++e)
            if (acc[r][e] > m1) { m1 = acc[r][e]; i1 = e; }
        float m2 = -INFINITY; int i2 = 0;
        #pragma unroll
        for (int e = 0; e < NE; ++e)
            if (e != i1 && acc[r][e] > m2) { m2 = acc[r][e]; i2 = e; }

        float s = 0.f, ex[NE];
        #pragma unroll
        for (int e = 0; e < NE; ++e) { ex[e] = __expf(acc[r][e] - m1); s += ex[e]; }
        const float inv = 1.f / s;
        #pragma unroll
        for (int e = 0; e < NE; ++e) meacc[e] += ex[e] * inv;

        const float e2v = __expf(m2 - m1);       // gate2/gate1
        const float w1  = 1.f / (1.f + e2v);     // g1/(g1+g2)
        const float w2  = 1.f - w1;

        if (lane == r) {
            const int row = row0 + r;
            idx[row]         = i1;
            idx[N_TOK + row] = i2;
            out[OUT_W + row]         = w1;
            out[OUT_W + N_TOK + row] = w2;
        }
    }
    if (lane == 0) {
        #pragma unroll
        for (int e = 0; e < NE; ++e) me_partial[gwave * NE + e] = meacc[e];
    }
}

// K2: single block, 1024 threads (16 waves). Stable counting-sort positions,
// expert counts/offsets, l_aux, scatter inverse permutation.
__global__ __launch_bounds__(1024) void k_finish(
    const int* __restrict__ idx, const float* __restrict__ me_partial,
    float* __restrict__ out)
{
    __shared__ int   chunk_hist[NCHUNK][NE];  // 16 KB; becomes exclusive scan
    __shared__ int   counts[NE];
    __shared__ int   offs[NE];
    __shared__ int   ce_cnt[NE];              // top-1 counts (t < N)
    __shared__ float me_red[64][NE];          // 4 KB

    const int tid  = threadIdx.x;
    const int lane = tid & 63;
    const int wave = tid >> 6;                // 0..15

    int myrank[16], myexp[16];

    // Phase 1: per-64-chunk histograms + intra-chunk stable ranks via ballot.
    const unsigned long long mlt = (1ull << lane) - 1ull;
    #pragma unroll
    for (int cc = 0; cc < 16; ++cc) {
        const int c = wave * 16 + cc;
        const int t = c * 64 + lane;
        const int e = idx[t];
        int rk = 0;
        #pragma unroll
        for (int eo = 0; eo < NE; ++eo) {
            unsigned long long m = __ballot(e == eo);
            if (e == eo)    rk = (int)__popcll(m & mlt);
            if (lane == eo) chunk_hist[c][eo] = (int)__popcll(m);
        }
        myrank[cc] = rk; myexp[cc] = e;
    }
    __syncthreads();

    // Phase 2: exclusive scan over 256 chunks, one expert per wave.
    if (wave < NE) {
        const int ecol = wave;
        int carry = 0;
        #pragma unroll
        for (int cc = 0; cc < 4; ++cc) {
            const int c = cc * 64 + lane;
            int v = chunk_hist[c][ecol];
            const int orig = v;
            #pragma unroll
            for (int off = 1; off < 64; off <<= 1) {
                int n = __shfl_up(v, off, 64);
                if (lane >= off) v += n;
            }
            const int excl = v - orig + carry;
            if (c == 128) ce_cnt[ecol] = excl;   // sum of chunks 0..127 = top-1 count
            chunk_hist[c][ecol] = excl;
            carry += __shfl(v, 63, 64);
        }
        if (lane == 0) counts[ecol] = carry;
    }
    __syncthreads();

    if (tid == 0) {
        int run = 0;
        for (int e = 0; e < NE; ++e) { offs[e] = run; run += counts[e]; }
    }
    // me partial reduction: 2048x16 -> 64x16
    {
        const int e = tid & 15, g0 = tid >> 4;  // g0 in [0,64)
        float sum = 0.f;
        for (int k = 0; k < GATE_WAVES / 64; ++k)   // 32
            sum += me_partial[(size_t)(g0 + 64 * k) * NE + e];
        me_red[g0][e] = sum;
    }
    __syncthreads();

    if (wave == 0 && lane < NE) {
        float me = 0.f;
        for (int g = 0; g < 64; ++g) me += me_red[g][lane];
        me *= (1.0f / N_TOK);
        const float ce = (float)ce_cnt[lane] * (1.0f / N_TOK);
        float la = me * ce * (float)NE;
        la += __shfl_xor(la, 8); la += __shfl_xor(la, 4);
        la += __shfl_xor(la, 2); la += __shfl_xor(la, 1);
        if (lane == 0) out[OUT_LAUX] = la;
        out[OUT_CNT + lane] = (float)counts[lane];
    }

    // Phase 3: final positions + inverse-permutation scatter.
    #pragma unroll
    for (int cc = 0; cc < 16; ++cc) {
        const int c = wave * 16 + cc;
        const int t = c * 64 + lane;
        const int e = myexp[cc];
        const int pos = chunk_hist[c][e] + offs[e] + myrank[cc];
        out[OUT_TPA + t]   = (float)pos;
        out[OUT_TPB + pos] = (float)t;
    }
}

extern "C" void kernel_launch(void* const* d_in, const int* in_sizes, int n_in,
                              void* d_out, int out_size, void* d_ws, size_t ws_size,
                              hipStream_t stream) {
    const float* x  = (const float*)d_in[0];   // [8192,4096] fp32
    const float* wg = (const float*)d_in[1];   // [16,4096] fp32
    // d_in[2] = k (=2), unused
    float* out = (float*)d_out;

    int*   idx        = (int*)d_ws;                                  // 64 KB
    float* me_partial = (float*)((char*)d_ws + TOKS * sizeof(int));  // 128 KB

    k_gates<<<GATE_BLOCKS, 256, 0, stream>>>(
        (const float4*)x, (const float4*)wg, idx, me_partial, out);
    k_finish<<<1, 1024, 0, stream>>>(idx, me_partial, out);
}

// Round 2
// 248.318 us; speedup vs baseline: 1.0989x; 1.0989x over previous
//
#include <hip/hip_runtime.h>
#include <math.h>

#define N_TOK 8192
#define DIM   4096
#define NE    16
#define TOKS  (2*N_TOK)        // 16384
#define NCHUNK (TOKS/64)       // 256
#define NSEG 4
#define SEGF4 (DIM/4/NSEG)     // 256 float4 per segment
#define D4 (DIM/4)             // 1024

// d_out layout (all float32):
// [0] l_aux | [1..16384] token_pos_after | [16385..32768] token_pos_before
// [32769..32784] expert_token_count | [32785..49168] weight
#define OUT_LAUX 0
#define OUT_TPA  1
#define OUT_TPB  (1+TOKS)
#define OUT_CNT  (1+2*TOKS)
#define OUT_W    (1+2*TOKS+NE)

// K1: partial logits. 8192 waves (2048 blocks x 256). Wave = 4 rows x 1 D-segment.
// x read exactly once (disjoint segments); Wg segment (64KB) re-read per wave from L2.
// Epilogue: 63-op pairwise-exchange tree -> lane l holds total for (row r=l>>4, e=l&15).
__global__ __launch_bounds__(256, 4) void k1_logits(
    const float4* __restrict__ x4, const float4* __restrict__ wg4,
    float* __restrict__ part)
{
    const int lane  = threadIdx.x & 63;
    const int wave  = threadIdx.x >> 6;
    const int gwave = blockIdx.x * 4 + wave;
    const int seg   = gwave & (NSEG - 1);
    const int row0  = (gwave >> 2) * 4;

    float acc[4][NE];
    #pragma unroll
    for (int r = 0; r < 4; ++r)
        #pragma unroll
        for (int e = 0; e < NE; ++e) acc[r][e] = 0.f;

    #pragma unroll 2
    for (int j = 0; j < SEGF4 / 64; ++j) {   // 4 iters
        const int col = seg * SEGF4 + j * 64 + lane;
        float4 xv0 = x4[(size_t)(row0 + 0) * D4 + col];
        float4 xv1 = x4[(size_t)(row0 + 1) * D4 + col];
        float4 xv2 = x4[(size_t)(row0 + 2) * D4 + col];
        float4 xv3 = x4[(size_t)(row0 + 3) * D4 + col];
        #pragma unroll
        for (int e = 0; e < NE; ++e) {
            float4 wv = wg4[e * D4 + col];
            acc[0][e] = fmaf(xv0.x, wv.x, acc[0][e]);
            acc[0][e] = fmaf(xv0.y, wv.y, acc[0][e]);
            acc[0][e] = fmaf(xv0.z, wv.z, acc[0][e]);
            acc[0][e] = fmaf(xv0.w, wv.w, acc[0][e]);
            acc[1][e] = fmaf(xv1.x, wv.x, acc[1][e]);
            acc[1][e] = fmaf(xv1.y, wv.y, acc[1][e]);
            acc[1][e] = fmaf(xv1.z, wv.z, acc[1][e]);
            acc[1][e] = fmaf(xv1.w, wv.w, acc[1][e]);
            acc[2][e] = fmaf(xv2.x, wv.x, acc[2][e]);
            acc[2][e] = fmaf(xv2.y, wv.y, acc[2][e]);
            acc[2][e] = fmaf(xv2.z, wv.z, acc[2][e]);
            acc[2][e] = fmaf(xv2.w, wv.w, acc[2][e]);
            acc[3][e] = fmaf(xv3.x, wv.x, acc[3][e]);
            acc[3][e] = fmaf(xv3.y, wv.y, acc[3][e]);
            acc[3][e] = fmaf(xv3.z, wv.z, acc[3][e]);
            acc[3][e] = fmaf(xv3.w, wv.w, acc[3][e]);
        }
    }

    // Tree-reduce 64 accumulators across 64 lanes: after stage s, lane bit s
    // has selected acc-index bit s. Lane l ends with sum over lanes of acc[l].
    float v[64];
    #pragma unroll
    for (int r = 0; r < 4; ++r)
        #pragma unroll
        for (int e = 0; e < NE; ++e) v[r * 16 + e] = acc[r][e];

    #pragma unroll
    for (int s = 0; s < 6; ++s) {
        const int step = 1 << s;
        const int hi = (lane >> s) & 1;
        #pragma unroll
        for (int i = 0; i < (64 >> (s + 1)); ++i) {
            float a = v[2 * i], b = v[2 * i + 1];
            float mine = hi ? b : a;
            float oth  = hi ? a : b;
            v[i] = mine + __shfl_xor(oth, step);
        }
    }
    // part[seg][row][e], coalesced 64-float store
    part[(size_t)seg * (N_TOK * NE) + (size_t)row0 * NE + lane] = v[0];
}

// K2: per-row epilogue + fused per-chunk ballots.
// One thread per row (8192 threads = 32 blocks). Wave w <-> top1-chunk w and
// top2-chunk 128+w (token order: [top1 rows 0..N) ++ [top2 rows 0..N)).
__global__ __launch_bounds__(256) void k2_route(
    const float* __restrict__ part, int* __restrict__ pr,
    int* __restrict__ hist, float* __restrict__ me_part,
    float* __restrict__ out)
{
    const int row   = blockIdx.x * 256 + threadIdx.x;
    const int lane  = threadIdx.x & 63;
    const int gwave = row >> 6;   // chunk index for top-1 half

    // deterministic segment-order sum
    float lg[NE];
    #pragma unroll
    for (int e = 0; e < NE; ++e) lg[e] = 0.f;
    #pragma unroll
    for (int s = 0; s < NSEG; ++s) {
        const float4* p4 = (const float4*)(part + (size_t)s * (N_TOK * NE) + (size_t)row * NE);
        #pragma unroll
        for (int q = 0; q < 4; ++q) {
            float4 t = p4[q];
            lg[q * 4 + 0] += t.x;
            lg[q * 4 + 1] += t.y;
            lg[q * 4 + 2] += t.z;
            lg[q * 4 + 3] += t.w;
        }
    }

    // top-2, strict > = lowest index on ties (matches lax.top_k)
    float m1 = -INFINITY; int i1 = 0;
    #pragma unroll
    for (int e = 0; e < NE; ++e)
        if (lg[e] > m1) { m1 = lg[e]; i1 = e; }
    float m2 = -INFINITY; int i2 = 0;
    #pragma unroll
    for (int e = 0; e < NE; ++e)
        if (e != i1 && lg[e] > m2) { m2 = lg[e]; i2 = e; }

    float ssum = 0.f, ex[NE];
    #pragma unroll
    for (int e = 0; e < NE; ++e) { ex[e] = __expf(lg[e] - m1); ssum += ex[e]; }
    const float inv = 1.f / ssum;

    const float e2v = __expf(m2 - m1);
    const float w1  = 1.f / (1.f + e2v);
    out[OUT_W + row]         = w1;
    out[OUT_W + N_TOK + row] = 1.f - w1;

    // per-wave me partial: butterfly each expert, lane e keeps expert e's sum
    float mymev = 0.f;
    #pragma unroll
    for (int e = 0; e < NE; ++e) {
        float mv = ex[e] * inv;
        mv += __shfl_xor(mv, 32); mv += __shfl_xor(mv, 16);
        mv += __shfl_xor(mv, 8);  mv += __shfl_xor(mv, 4);
        mv += __shfl_xor(mv, 2);  mv += __shfl_xor(mv, 1);
        if (lane == e) mymev = mv;
    }
    if (lane < NE) me_part[gwave * NE + lane] = mymev;

    // stable intra-chunk ranks + chunk histograms via ballot
    const unsigned long long mlt = (1ull << lane) - 1ull;
    int rk1 = 0, rk2 = 0;
    #pragma unroll
    for (int eo = 0; eo < NE; ++eo) {
        unsigned long long mA = __ballot(i1 == eo);
        unsigned long long mB = __ballot(i2 == eo);
        if (i1 == eo) rk1 = (int)__popcll(mA & mlt);
        if (i2 == eo) rk2 = (int)__popcll(mB & mlt);
        if (lane == eo) {
            hist[gwave * NE + eo]                 = (int)__popcll(mA);
            hist[(NCHUNK / 2 + gwave) * NE + eo]  = (int)__popcll(mB);
        }
    }
    pr[row]         = i1 | (rk1 << 8);
    pr[N_TOK + row] = i2 | (rk2 << 8);
}

// K3: single small block — scan 256x16 chunk hists, counts/offsets, l_aux.
__global__ __launch_bounds__(1024) void k3_scan(
    const int* __restrict__ hist, const float* __restrict__ me_part,
    int* __restrict__ base, float* __restrict__ out)
{
    __shared__ int   sh[NCHUNK][NE];   // exclusive scans (16 KB)
    __shared__ int   counts[NE];
    __shared__ int   offs[NE];
    __shared__ int   ce_cnt[NE];
    __shared__ float me_red[64][NE];

    const int tid  = threadIdx.x;
    const int lane = tid & 63;
    const int wave = tid >> 6;   // 0..15

    if (wave < NE) {
        const int ecol = wave;
        int carry = 0;
        #pragma unroll
        for (int cc = 0; cc < 4; ++cc) {
            const int c = cc * 64 + lane;
            int v = hist[c * NE + ecol];
            const int orig = v;
            #pragma unroll
            for (int off = 1; off < 64; off <<= 1) {
                int n = __shfl_up(v, off, 64);
                if (lane >= off) v += n;
            }
            const int excl = v - orig + carry;
            if (c == NCHUNK / 2) ce_cnt[ecol] = excl;  // top-1 total
            sh[c][ecol] = excl;
            carry += __shfl(v, 63, 64);
        }
        if (lane == 0) counts[ecol] = carry;
    }
    __syncthreads();

    if (tid == 0) {
        int run = 0;
        for (int e = 0; e < NE; ++e) { offs[e] = run; run += counts[e]; }
    }
    {
        const int e = tid & 15, g = tid >> 4;  // g in [0,64)
        me_red[g][e] = me_part[g * NE + e] + me_part[(g + 64) * NE + e];
    }
    __syncthreads();

    if (wave == 0 && lane < NE) {
        float me = 0.f;
        for (int g = 0; g < 64; ++g) me += me_red[g][lane];
        me *= (1.0f / N_TOK);
        const float ce = (float)ce_cnt[lane] * (1.0f / N_TOK);
        float la = me * ce * (float)NE;
        la += __shfl_xor(la, 8); la += __shfl_xor(la, 4);
        la += __shfl_xor(la, 2); la += __shfl_xor(la, 1);
        if (lane == 0) out[OUT_LAUX] = la;
        out[OUT_CNT + lane] = (float)counts[lane];
    }

    // base[c][e] = exclusive chunk scan + expert offset
    #pragma unroll
    for (int k = 0; k < (NCHUNK * NE) / 1024; ++k) {  // 4
        const int i = k * 1024 + tid;
        base[i] = ((const int*)sh)[i] + offs[i & 15];
    }
}

// K4: final positions + inverse permutation. 16384 threads = 64 blocks.
__global__ __launch_bounds__(256) void k4_place(
    const int* __restrict__ pr, const int* __restrict__ base,
    float* __restrict__ out)
{
    const int t  = blockIdx.x * 256 + threadIdx.x;
    const int v  = pr[t];
    const int e  = v & 255;
    const int rk = v >> 8;
    const int c  = t >> 6;
    const int pos = base[c * NE + e] + rk;
    out[OUT_TPA + t]   = (float)pos;
    out[OUT_TPB + pos] = (float)t;
}

extern "C" void kernel_launch(void* const* d_in, const int* in_sizes, int n_in,
                              void* d_out, int out_size, void* d_ws, size_t ws_size,
                              hipStream_t stream) {
    const float* x  = (const float*)d_in[0];   // [8192,4096] fp32
    const float* wg = (const float*)d_in[1];   // [16,4096] fp32
    float* out = (float*)d_out;

    char* w = (char*)d_ws;
    float* part    = (float*)w;                          // 4*8192*16*4 = 2 MB
    w += (size_t)NSEG * N_TOK * NE * sizeof(float);
    int* pr        = (int*)w;   w += TOKS * sizeof(int);        // 64 KB
    int* hist      = (int*)w;   w += NCHUNK * NE * sizeof(int); // 16 KB
    int* base      = (int*)w;   w += NCHUNK * NE * sizeof(int); // 16 KB
    float* me_part = (float*)w;                                  // 8 KB

    k1_logits<<<(N_TOK / 4) * NSEG / 4, 256, 0, stream>>>(
        (const float4*)x, (const float4*)wg, part);
    k2_route<<<N_TOK / 256, 256, 0, stream>>>(part, pr, hist, me_part, out);
    k3_scan<<<1, 1024, 0, stream>>>(hist, me_part, base, out);
    k4_place<<<TOKS / 256, 256, 0, stream>>>(pr, base, out);
}

// Round 3
// 224.445 us; speedup vs baseline: 1.2158x; 1.1064x over previous
//
#include <hip/hip_runtime.h>
#include <math.h>

#define N_TOK 8192
#define DIM   4096
#define NE    16
#define TOKS  (2*N_TOK)        // 16384
#define NCHUNK (TOKS/64)       // 256
#define D4    (DIM/4)          // 1024 float4 per row
#define SEGF4 128              // float4 per D-segment (512 cols)
#define NSEG  (D4/SEGF4)       // 8
#define K1_THREADS 512
#define K1_BLOCKS  256
#define ROWS_PER_BLOCK 32      // 8 waves x 4 rows
#define GATE_WAVES (K1_BLOCKS*8)   // 2048 row-waves (4 rows each)

// d_out layout (all float32):
// [0] l_aux | [1..16384] token_pos_after | [16385..32768] token_pos_before
// [32769..32784] expert_token_count | [32785..49168] weight
#define OUT_LAUX 0
#define OUT_TPA  1
#define OUT_TPB  (1+TOKS)
#define OUT_CNT  (1+2*TOKS)
#define OUT_W    (1+2*TOKS+NE)

#define AS3(p) ((__attribute__((address_space(3))) void*)(p))
#define AS1(p) ((const __attribute__((address_space(1))) void*)(p))

// K1: logits + softmax + top-2 + weights + me partials, Wg staged in LDS.
// 256 blocks x 512 threads, 1 block/CU. Wave = 4 rows, full D.
// Wg enters the CU exactly once (256 KB staged via global_load_lds);
// compute-side Wg reads are ds_read_b128 (DS pipe, no vmem miss slots).
__global__ __launch_bounds__(K1_THREADS) void k1_gate(
    const float4* __restrict__ x4, const float4* __restrict__ wg4,
    int* __restrict__ idx, float* __restrict__ me_part,
    float* __restrict__ out)
{
    __shared__ float4 sbuf[2][NE][SEGF4];   // 2 x 32 KB

    const int tid  = threadIdx.x;
    const int lane = tid & 63;
    const int wave = tid >> 6;              // 0..7
    const int row0 = blockIdx.x * ROWS_PER_BLOCK + wave * 4;

    // ---- stage segment s into sbuf[b] (wave-uniform LDS base + lane*16) ----
    // element i in [0,2048): e = i>>7, c = i&127; thread handles i = it*512+tid
    auto stage = [&](int s, int b) {
        #pragma unroll
        for (int it = 0; it < 4; ++it) {
            const int i = it * K1_THREADS + tid;
            const int e = i >> 7, c = i & 127;
            const float4* g = wg4 + (size_t)e * D4 + s * SEGF4 + c;
            char* lbase = (char*)&sbuf[b][0][0] +
                          (size_t)(it * K1_THREADS + (tid & ~63)) * 16;
            __builtin_amdgcn_global_load_lds(AS1(g), AS3(lbase), 16, 0, 0);
        }
    };

    float acc[4][NE];
    #pragma unroll
    for (int r = 0; r < 4; ++r)
        #pragma unroll
        for (int e = 0; e < NE; ++e) acc[r][e] = 0.f;

    stage(0, 0);
    float4 xc[2][4];
    #pragma unroll
    for (int j = 0; j < 2; ++j)
        #pragma unroll
        for (int r = 0; r < 4; ++r)
            xc[j][r] = x4[(size_t)(row0 + r) * D4 + j * 64 + lane];

    int p = 0;
    for (int s = 0; s < NSEG; ++s) {
        __syncthreads();   // sbuf[p] staged, safe to read; sbuf[p^1] free
        float4 xn[2][4];
        if (s < NSEG - 1) {
            stage(s + 1, p ^ 1);
            const int colb = (s + 1) * SEGF4;
            #pragma unroll
            for (int j = 0; j < 2; ++j)
                #pragma unroll
                for (int r = 0; r < 4; ++r)
                    xn[j][r] = x4[(size_t)(row0 + r) * D4 + colb + j * 64 + lane];
        }
        #pragma unroll
        for (int j = 0; j < 2; ++j) {
            #pragma unroll
            for (int e = 0; e < NE; ++e) {
                const float4 wv = sbuf[p][e][j * 64 + lane];
                #pragma unroll
                for (int r = 0; r < 4; ++r) {
                    acc[r][e] = fmaf(xc[j][r].x, wv.x, acc[r][e]);
                    acc[r][e] = fmaf(xc[j][r].y, wv.y, acc[r][e]);
                    acc[r][e] = fmaf(xc[j][r].z, wv.z, acc[r][e]);
                    acc[r][e] = fmaf(xc[j][r].w, wv.w, acc[r][e]);
                }
            }
        }
        #pragma unroll
        for (int j = 0; j < 2; ++j)
            #pragma unroll
            for (int r = 0; r < 4; ++r) xc[j][r] = xn[j][r];
        p ^= 1;
    }

    // ---- epilogue: per-(r,e) butterfly (spill-free, R1-proven) ----
    #pragma unroll
    for (int r = 0; r < 4; ++r)
        #pragma unroll
        for (int e = 0; e < NE; ++e) {
            float v = acc[r][e];
            v += __shfl_xor(v, 32); v += __shfl_xor(v, 16);
            v += __shfl_xor(v, 8);  v += __shfl_xor(v, 4);
            v += __shfl_xor(v, 2);  v += __shfl_xor(v, 1);
            acc[r][e] = v;
        }

    float meacc[NE];
    #pragma unroll
    for (int e = 0; e < NE; ++e) meacc[e] = 0.f;

    #pragma unroll
    for (int r = 0; r < 4; ++r) {
        // top-2; strict > keeps lowest index on ties (matches lax.top_k)
        float m1 = -INFINITY; int i1 = 0;
        #pragma unroll
        for (int e = 0; e < NE; ++e)
            if (acc[r][e] > m1) { m1 = acc[r][e]; i1 = e; }
        float m2 = -INFINITY; int i2 = 0;
        #pragma unroll
        for (int e = 0; e < NE; ++e)
            if (e != i1 && acc[r][e] > m2) { m2 = acc[r][e]; i2 = e; }

        float ssum = 0.f, ex[NE];
        #pragma unroll
        for (int e = 0; e < NE; ++e) { ex[e] = __expf(acc[r][e] - m1); ssum += ex[e]; }
        const float inv = 1.f / ssum;
        #pragma unroll
        for (int e = 0; e < NE; ++e) meacc[e] += ex[e] * inv;

        const float e2v = __expf(m2 - m1);
        const float w1  = 1.f / (1.f + e2v);
        if (lane == r) {
            const int row = row0 + r;
            idx[row]         = i1;
            idx[N_TOK + row] = i2;
            out[OUT_W + row]         = w1;
            out[OUT_W + N_TOK + row] = 1.f - w1;
        }
    }
    if (lane == 0) {
        const int gwave = blockIdx.x * 8 + wave;
        #pragma unroll
        for (int e = 0; e < NE; ++e) me_part[gwave * NE + e] = meacc[e];
    }
}

// K2: stable intra-chunk ranks + per-chunk histograms. 64 blocks x 256.
// Wave = one 64-token chunk.
__global__ __launch_bounds__(256) void k2_rank(
    const int* __restrict__ idx, int* __restrict__ pr, int* __restrict__ hist)
{
    const int lane = threadIdx.x & 63;
    const int c    = blockIdx.x * 4 + (threadIdx.x >> 6);
    const int t    = c * 64 + lane;
    const int e    = idx[t];

    const unsigned long long mlt = (1ull << lane) - 1ull;
    int rk = 0;
    #pragma unroll
    for (int eo = 0; eo < NE; ++eo) {
        unsigned long long m = __ballot(e == eo);
        if (e == eo)    rk = (int)__popcll(m & mlt);
        if (lane == eo) hist[c * NE + eo] = (int)__popcll(m);
    }
    pr[t] = e | (rk << 8);
}

// K3: scan 256x16 chunk hists -> base offsets; counts; l_aux. 1 block.
__global__ __launch_bounds__(1024) void k3_scan(
    const int* __restrict__ hist, const float* __restrict__ me_part,
    int* __restrict__ base, float* __restrict__ out)
{
    __shared__ int   sh[NCHUNK][NE];
    __shared__ int   counts[NE];
    __shared__ int   offs[NE];
    __shared__ int   ce_cnt[NE];
    __shared__ float me_red[64][NE];

    const int tid  = threadIdx.x;
    const int lane = tid & 63;
    const int wave = tid >> 6;   // 0..15

    if (wave < NE) {
        const int ecol = wave;
        int carry = 0;
        #pragma unroll
        for (int cc = 0; cc < 4; ++cc) {
            const int c = cc * 64 + lane;
            int v = hist[c * NE + ecol];
            const int orig = v;
            #pragma unroll
            for (int off = 1; off < 64; off <<= 1) {
                int n = __shfl_up(v, off, 64);
                if (lane >= off) v += n;
            }
            const int excl = v - orig + carry;
            if (c == NCHUNK / 2) ce_cnt[ecol] = excl;  // top-1 total
            sh[c][ecol] = excl;
            carry += __shfl(v, 63, 64);
        }
        if (lane == 0) counts[ecol] = carry;
    }
    __syncthreads();

    if (tid == 0) {
        int run = 0;
        for (int e = 0; e < NE; ++e) { offs[e] = run; run += counts[e]; }
    }
    {   // me partial reduction: 2048x16 -> 64x16
        const int e = tid & 15, g0 = tid >> 4;  // g0 in [0,64)
        float sum = 0.f;
        for (int k = 0; k < GATE_WAVES / 64; ++k)   // 32
            sum += me_part[(size_t)(g0 + 64 * k) * NE + e];
        me_red[g0][e] = sum;
    }
    __syncthreads();

    if (wave == 0 && lane < NE) {
        float me = 0.f;
        for (int g = 0; g < 64; ++g) me += me_red[g][lane];
        me *= (1.0f / N_TOK);
        const float ce = (float)ce_cnt[lane] * (1.0f / N_TOK);
        float la = me * ce * (float)NE;
        la += __shfl_xor(la, 8); la += __shfl_xor(la, 4);
        la += __shfl_xor(la, 2); la += __shfl_xor(la, 1);
        if (lane == 0) out[OUT_LAUX] = la;
        out[OUT_CNT + lane] = (float)counts[lane];
    }

    #pragma unroll
    for (int k = 0; k < (NCHUNK * NE) / 1024; ++k) {  // 4
        const int i = k * 1024 + tid;
        base[i] = ((const int*)sh)[i] + offs[i & 15];
    }
}

// K4: final positions + inverse permutation. 64 blocks x 256.
__global__ __launch_bounds__(256) void k4_place(
    const int* __restrict__ pr, const int* __restrict__ base,
    float* __restrict__ out)
{
    const int t  = blockIdx.x * 256 + threadIdx.x;
    const int v  = pr[t];
    const int e  = v & 255;
    const int rk = v >> 8;
    const int c  = t >> 6;
    const int pos = base[c * NE + e] + rk;
    out[OUT_TPA + t]   = (float)pos;
    out[OUT_TPB + pos] = (float)t;
}

extern "C" void kernel_launch(void* const* d_in, const int* in_sizes, int n_in,
                              void* d_out, int out_size, void* d_ws, size_t ws_size,
                              hipStream_t stream) {
    const float* x  = (const float*)d_in[0];   // [8192,4096] fp32
    const float* wg = (const float*)d_in[1];   // [16,4096] fp32
    float* out = (float*)d_out;

    char* w = (char*)d_ws;
    int*   idx     = (int*)w;   w += TOKS * sizeof(int);        // 64 KB
    int*   pr      = (int*)w;   w += TOKS * sizeof(int);        // 64 KB
    int*   hist    = (int*)w;   w += NCHUNK * NE * sizeof(int); // 16 KB
    int*   base    = (int*)w;   w += NCHUNK * NE * sizeof(int); // 16 KB
    float* me_part = (float*)w;                                 // 128 KB

    k1_gate<<<K1_BLOCKS, K1_THREADS, 0, stream>>>(
        (const float4*)x, (const float4*)wg, idx, me_part, out);
    k2_rank<<<NCHUNK / 4, 256, 0, stream>>>(idx, pr, hist);
    k3_scan<<<1, 1024, 0, stream>>>(hist, me_part, base, out);
    k4_place<<<TOKS / 256, 256, 0, stream>>>(pr, base, out);
}